// Round 6
// baseline (505.636 us; speedup 1.0000x reference)
//
#include <hip/hip_runtime.h>
#include <hip/hip_bf16.h>

// NonlinearReservoirCell: B=262144 rows, M=3 independent tiny MLPs
//   free_water = last_free_water + sum_n runoff
//   a1 = relu(runoff @ W1 + b1)   (256 -> 256)
//   a2 = relu(a1 @ W2 + b2)       (256 -> 128)
//   ratio = sigmoid(a2 @ W3 + b3) (128 -> 1)
//   flow = fw*ratio + last_flow*(1-ratio);  new_fw = fw - flow
// R6: wave-specialized dataflow to cut LDS+VALU ~2x at identical memory
//     traffic (discriminates additive-pipe theory vs L3-read-BW wall).
//     Wave wv owns h in [64wv,64wv+64) for L1 and k2 in [32wv,32wv+32) for
//     L2. W1/W2 fragments stream per-kk from L2 global (no LDS for weights).
//     a1 crosses waves via one XOR-swizzled LDS panel. Runoff reg-staged
//     (verified R4 pack/swizzle) under L1 compute cover. 3 barriers/unit.

#define B_TOT 262144
#define M_    3
#define N_    256
#define H1_   256
#define H2_   128
#define BM_   (B_TOT * M_)

typedef __bf16 bf16_t;
typedef __bf16  bf16x8 __attribute__((ext_vector_type(8)));
typedef float   f32x16 __attribute__((ext_vector_type(16)));
typedef float   f32x4  __attribute__((ext_vector_type(4)));

__device__ __forceinline__ unsigned pack_bf2(float lo, float hi) {
  union { bf16_t b; unsigned short u; } a, c;
  a.b = (bf16_t)lo; c.b = (bf16_t)hi;
  return ((unsigned)c.u << 16) | (unsigned)a.u;
}

// ---------------------------------------------------------------------------
// Prep: transpose + cvt weights into per-lane MFMA A-fragment order (bf16).
// w1s[m][kk(16)][t(8)][lane(64)][ii(8)] = bf16(W1[m][n=16kk+8*(lane>>5)+ii][h=32t+(lane&31)])
// w2s[m][kk2(16)][t2(4)][lane(64)][ii(8)] = bf16(W2[m][h=16kk2+8*(lane>>5)+ii][k2=32t2+(lane&31)])
// ---------------------------------------------------------------------------
__global__ __launch_bounds__(256) void prep_weights(
    const float* __restrict__ W1, const float* __restrict__ W2,
    bf16_t* __restrict__ w1s, bf16_t* __restrict__ w2s)
{
  int id = blockIdx.x * 256 + threadIdx.x;
  const int NW1 = M_ * 16 * 8 * 64;   // 24576 groups of 8
  const int NW2 = M_ * 16 * 4 * 64;   // 12288 groups of 8
  if (id < NW1) {
    int lane = id & 63;
    int t    = (id >> 6) & 7;
    int kk   = (id >> 9) & 15;
    int m    = id >> 13;
    int h  = 32 * t + (lane & 31);
    int n0 = 16 * kk + 8 * (lane >> 5);
    bf16x8 v;
#pragma unroll
    for (int ii = 0; ii < 8; ++ii)
      v[ii] = (bf16_t)W1[((size_t)m * N_ + (n0 + ii)) * H1_ + h];
    *reinterpret_cast<bf16x8*>(&w1s[(size_t)id * 8]) = v;
  } else if (id < NW1 + NW2) {
    int j    = id - NW1;
    int lane = j & 63;
    int t2   = (j >> 6) & 3;
    int kk2  = (j >> 8) & 15;
    int m    = j >> 12;
    int k2 = 32 * t2 + (lane & 31);
    int h0 = 16 * kk2 + 8 * (lane >> 5);
    bf16x8 v;
#pragma unroll
    for (int ii = 0; ii < 8; ++ii)
      v[ii] = (bf16_t)W2[((size_t)m * H1_ + (h0 + ii)) * H2_ + k2];
    *reinterpret_cast<bf16x8*>(&w2s[(size_t)j * 8]) = v;
  }
}

// ---------------------------------------------------------------------------
// Main kernel. grid = 768 (bid>>8 = m, bid&255 = 1024-row chunk).
// Block = 4 waves, 8 units of 128 rows. Wave wv: L1 h-slice 64wv..64wv+63,
// L2 k2-slice 32wv..32wv+31. 1 block/CU (LDS 133 KB).
// ---------------------------------------------------------------------------
__global__ __launch_bounds__(256, 1) void reservoir_kernel(
    const float* __restrict__ last_flow,
    const float* __restrict__ last_fw,
    const float* __restrict__ runoff,
    const float* __restrict__ b1,
    const float* __restrict__ b2,
    const float* __restrict__ W3,
    const float* __restrict__ b3,
    const bf16_t* __restrict__ w1s,
    const bf16_t* __restrict__ w2s,
    float* __restrict__ out)
{
  // panels [128 rows][256 bf16], 16-B granule swizzle phys = g ^ (row&15)
  __shared__ alignas(16) bf16_t sX[128 * 256];   // runoff panel, 64 KB
  __shared__ alignas(16) bf16_t sY[128 * 256];   // a1 panel,     64 KB
  __shared__ alignas(16) float  sB1f[H1_];
  __shared__ alignas(16) float  sB2f[H2_];
  __shared__ alignas(16) float  sW3f[H2_];
  __shared__ alignas(16) float  sPart[4][128];
  __shared__ alignas(16) float  sRsum[128];

  const int tid  = threadIdx.x;
  const int lane = tid & 63;
  const int wv   = tid >> 6;
  const int hi   = lane >> 5;
  const int r    = lane & 31;

  const int m        = blockIdx.x >> 8;
  const size_t rbase = (size_t)(blockIdx.x & 255) * 1024;

  const bf16_t* w1base = w1s + (size_t)m * 65536;
  const bf16_t* w2base = w2s + (size_t)m * 32768;
  const float   b3v    = b3[m];

  // tables
  sB1f[tid] = b1[m * H1_ + tid];
  if (tid < H2_) { sB2f[tid] = b2[m * H2_ + tid]; sW3f[tid] = W3[m * H2_ + tid]; }

  f32x4 tmp[8];
  uint2 pkbuf[4][8];

#define STAGE_LOAD(grp, nu) {                                                 \
    size_t gb = rbase + (size_t)(nu) * 128 + wv * 32 + (grp) * 8;             \
    _Pragma("unroll")                                                         \
    for (int j = 0; j < 8; ++j)                                               \
      tmp[j] = *reinterpret_cast<const f32x4*>(                               \
          runoff + ((gb + j) * M_ + m) * N_ + lane * 4);                      \
  }
#define STAGE_PACK(grp) {                                                     \
    _Pragma("unroll")                                                         \
    for (int j = 0; j < 8; ++j) {                                             \
      pkbuf[grp][j].x = pack_bf2(tmp[j][0], tmp[j][1]);                       \
      pkbuf[grp][j].y = pack_bf2(tmp[j][2], tmp[j][3]);                       \
    }                                                                         \
  }
#define STAGE_WRITE_ALL() {                                                   \
    _Pragma("unroll")                                                         \
    for (int g2 = 0; g2 < 4; ++g2) {                                          \
      _Pragma("unroll")                                                       \
      for (int j = 0; j < 8; ++j) {                                           \
        int prow = wv * 32 + g2 * 8 + j;                                      \
        int p8   = lane ^ ((prow & 15) << 1);                                 \
        *reinterpret_cast<uint2*>(&sX[prow * 256 + p8 * 4]) = pkbuf[g2][j];   \
      }                                                                       \
    }                                                                         \
  }

  // prologue: stage unit 0
#pragma unroll
  for (int g2 = 0; g2 < 4; ++g2) { STAGE_LOAD(g2, 0); STAGE_PACK(g2); }
  STAGE_WRITE_ALL();
  __syncthreads();

  for (int u = 0; u < 8; ++u) {
    // ---------------- Layer 1 ----------------
    f32x16 acc1[2][4];
#pragma unroll
    for (int t = 0; t < 2; ++t)
#pragma unroll
      for (int rg = 0; rg < 4; ++rg)
        acc1[t][rg] = f32x16{};

    float rsum = 0.f;
    bf16x8 afc0 = *reinterpret_cast<const bf16x8*>(
        w1base + 0 * 4096 + (2 * wv + 0) * 512 + lane * 8);
    bf16x8 afc1 = *reinterpret_cast<const bf16x8*>(
        w1base + 0 * 4096 + (2 * wv + 1) * 512 + lane * 8);

#define L1_STEP(kk) {                                                         \
    bf16x8 afn0{}, afn1{};                                                    \
    if ((kk) < 15) {                                                          \
      afn0 = *reinterpret_cast<const bf16x8*>(                                \
          w1base + ((kk) + 1) * 4096 + (2 * wv + 0) * 512 + lane * 8);        \
      afn1 = *reinterpret_cast<const bf16x8*>(                                \
          w1base + ((kk) + 1) * 4096 + (2 * wv + 1) * 512 + lane * 8);        \
    }                                                                         \
    _Pragma("unroll")                                                         \
    for (int rg = 0; rg < 4; ++rg) {                                          \
      bf16x8 bf = *reinterpret_cast<const bf16x8*>(                           \
          &sX[(rg * 32 + r) * 256 + (((2 * (kk) + hi) ^ (r & 15)) * 8)]);     \
      if (rg == wv) {                                                         \
        _Pragma("unroll")                                                     \
        for (int j = 0; j < 8; ++j) rsum += (float)bf[j];                     \
      }                                                                       \
      acc1[0][rg] = __builtin_amdgcn_mfma_f32_32x32x16_bf16(afc0, bf, acc1[0][rg], 0, 0, 0); \
      acc1[1][rg] = __builtin_amdgcn_mfma_f32_32x32x16_bf16(afc1, bf, acc1[1][rg], 0, 0, 0); \
    }                                                                         \
    afc0 = afn0; afc1 = afn1;                                                 \
  }

    if (u < 7) { STAGE_LOAD(0, u + 1); }
    L1_STEP(0)  L1_STEP(1)  L1_STEP(2)  L1_STEP(3)
    if (u < 7) { STAGE_PACK(0); STAGE_LOAD(1, u + 1); }
    L1_STEP(4)  L1_STEP(5)  L1_STEP(6)  L1_STEP(7)
    if (u < 7) { STAGE_PACK(1); STAGE_LOAD(2, u + 1); }
    L1_STEP(8)  L1_STEP(9)  L1_STEP(10) L1_STEP(11)
    if (u < 7) { STAGE_PACK(2); STAGE_LOAD(3, u + 1); }
    L1_STEP(12) L1_STEP(13) L1_STEP(14) L1_STEP(15)
    if (u < 7) { STAGE_PACK(3); }

    rsum += __shfl_xor(rsum, 32, 64);

    __syncthreads();   // bar1: everyone done reading sX / sY(prev L2)

    if (u < 7) STAGE_WRITE_ALL();            // R[u+1] -> sX
    if (hi == 0) sRsum[wv * 32 + r] = rsum;

    // a1 = relu(acc1 + b1) -> sY (bf16, swizzled)
#pragma unroll
    for (int t = 0; t < 2; ++t) {
      float2 b1p[8];
#pragma unroll
      for (int j = 0; j < 8; ++j) {
        int hl = 2 * (j & 1) + 8 * (j >> 1) + 4 * hi;
        b1p[j] = *reinterpret_cast<const float2*>(&sB1f[wv * 64 + t * 32 + hl]);
      }
#pragma unroll
      for (int rg = 0; rg < 4; ++rg) {
#pragma unroll
        for (int j = 0; j < 8; ++j) {
          int hl = 2 * (j & 1) + 8 * (j >> 1) + 4 * hi;
          int h  = wv * 64 + t * 32 + hl;
          unsigned val = pack_bf2(fmaxf(acc1[t][rg][2 * j]     + b1p[j].x, 0.f),
                                  fmaxf(acc1[t][rg][2 * j + 1] + b1p[j].y, 0.f));
          int row = rg * 32 + r;
          *reinterpret_cast<unsigned*>(
              &sY[row * 256 + (((h >> 3) ^ (row & 15)) * 8 + (h & 7))]) = val;
        }
      }
    }

    __syncthreads();   // bar2: sX(u+1) + sY(a1) + sRsum visible

    // ---------------- Layer 2 (k2-slice = wv) ----------------
    f32x16 acc2[4];
#pragma unroll
    for (int rg = 0; rg < 4; ++rg) acc2[rg] = f32x16{};

    bf16x8 wfc = *reinterpret_cast<const bf16x8*>(
        w2base + 0 * 2048 + wv * 512 + lane * 8);

#define L2_STEP(kk2) {                                                        \
    bf16x8 wfn{};                                                             \
    if ((kk2) < 15)                                                           \
      wfn = *reinterpret_cast<const bf16x8*>(                                 \
          w2base + ((kk2) + 1) * 2048 + wv * 512 + lane * 8);                 \
    _Pragma("unroll")                                                         \
    for (int rg = 0; rg < 4; ++rg) {                                          \
      bf16x8 bf = *reinterpret_cast<const bf16x8*>(                           \
          &sY[(rg * 32 + r) * 256 + (((2 * (kk2) + hi) ^ (r & 15)) * 8)]);    \
      acc2[rg] = __builtin_amdgcn_mfma_f32_32x32x16_bf16(wfc, bf, acc2[rg], 0, 0, 0); \
    }                                                                         \
    wfc = wfn;                                                                \
  }

    L2_STEP(0)  L2_STEP(1)  L2_STEP(2)  L2_STEP(3)
    L2_STEP(4)  L2_STEP(5)  L2_STEP(6)  L2_STEP(7)
    L2_STEP(8)  L2_STEP(9)  L2_STEP(10) L2_STEP(11)
    L2_STEP(12) L2_STEP(13) L2_STEP(14) L2_STEP(15)

    // partial dot with W3 over this wave's k2 slice
    float b2r[16], w3r[16];
#pragma unroll
    for (int e = 0; e < 16; ++e) {
      int k2 = wv * 32 + (e & 3) + 8 * (e >> 2) + 4 * hi;
      b2r[e] = sB2f[k2];
      w3r[e] = sW3f[k2];
    }
#pragma unroll
    for (int rg = 0; rg < 4; ++rg) {
      float part = 0.f;
#pragma unroll
      for (int e = 0; e < 16; ++e)
        part += fmaxf(acc2[rg][e] + b2r[e], 0.f) * w3r[e];
      part += __shfl_xor(part, 32, 64);
      if (hi == 0) sPart[wv][rg * 32 + r] = part;
    }

    __syncthreads();   // bar3: partials visible

    // ---------------- epilogue: one thread per row ----------------
    if (tid < 128) {
      const size_t grow = rbase + (size_t)u * 128 + tid;
      const size_t oi   = grow * M_ + m;
      const float pt    = sPart[0][tid] + sPart[1][tid] + sPart[2][tid]
                        + sPart[3][tid] + b3v;
      const float ratio = 1.0f / (1.0f + __expf(-pt));
      const float fw    = last_fw[oi] + sRsum[tid];
      const float lf    = last_flow[oi];
      const float flow  = fw * ratio + lf * (1.0f - ratio);
      out[oi]       = fw - flow;   // new_free_water
      out[BM_ + oi] = flow;        // flow
    }
  }

#undef STAGE_LOAD
#undef STAGE_PACK
#undef STAGE_WRITE_ALL
#undef L1_STEP
#undef L2_STEP
}

// ---------------------------------------------------------------------------
extern "C" void kernel_launch(void* const* d_in, const int* in_sizes, int n_in,
                              void* d_out, int out_size, void* d_ws, size_t ws_size,
                              hipStream_t stream) {
  const float* last_flow = (const float*)d_in[0];
  const float* last_fw   = (const float*)d_in[1];
  const float* runoff    = (const float*)d_in[2];
  const float* W1 = (const float*)d_in[3];
  const float* b1 = (const float*)d_in[4];
  const float* W2 = (const float*)d_in[5];
  const float* b2 = (const float*)d_in[6];
  const float* W3 = (const float*)d_in[7];
  const float* b3 = (const float*)d_in[8];
  float* out = (float*)d_out;

  bf16_t* w1s = (bf16_t*)d_ws;                    // 3*65536 bf16 = 384 KB
  bf16_t* w2s = w1s + (size_t)M_ * 65536;         // 3*32768 bf16 = 192 KB

  prep_weights<<<144, 256, 0, stream>>>(W1, W2, w1s, w2s);

  reservoir_kernel<<<768, 256, 0, stream>>>(last_flow, last_fw, runoff,
                                            b1, b2, W3, b3, w1s, w2s, out);
}